// Round 13
// baseline (847.042 us; speedup 1.0000x reference)
//
#include <hip/hip_runtime.h>
#include <hip/hip_bf16.h>
#include <stdint.h>

// Problem constants: B=4, S=2048, IN=4096, OUT=11008
#define M_DIM 8192   // B*S
#define N_DIM 11008  // OUT
#define K_DIM 4096   // IN
#define NGROUP 32    // K_DIM/128

#define BM 128
#define BN 256
#define BK 32
#define NT (K_DIM / BK)  // 128 K-tiles

typedef __attribute__((ext_vector_type(4))) float f32x4;
typedef __attribute__((ext_vector_type(8))) short short8;
typedef __attribute__((ext_vector_type(8))) __bf16 bf16x8;

static_assert(M_DIM % BM == 0 && N_DIM % BN == 0 && K_DIM % BK == 0, "tiling");
static_assert(NT % 2 == 0, "epilogue handles last two tiles");

__device__ __forceinline__ unsigned short f2bf(float f) {
  union { float f; unsigned int u; } v; v.f = f;
  unsigned int r = v.u + 0x7FFFu + ((v.u >> 16) & 1u);  // RNE
  return (unsigned short)(r >> 16);
}

// ---------- prepass 1: x fp32 -> bf16 ----------
__global__ __launch_bounds__(256) void cvt_x_kernel(const float* __restrict__ x,
                                                    unsigned short* __restrict__ xb) {
  size_t i = ((size_t)blockIdx.x * 256 + threadIdx.x) * 8;
  float4 a = *(const float4*)(x + i);
  float4 b = *(const float4*)(x + i + 4);
  short8 o;
  o[0] = (short)f2bf(a.x); o[1] = (short)f2bf(a.y);
  o[2] = (short)f2bf(a.z); o[3] = (short)f2bf(a.w);
  o[4] = (short)f2bf(b.x); o[5] = (short)f2bf(b.y);
  o[6] = (short)f2bf(b.z); o[7] = (short)f2bf(b.w);
  *(short8*)(xb + i) = o;
}

// ---------- prepass 2: dequant packed int4 -> bf16 W[N][K] ----------
__global__ __launch_bounds__(256) void dequant_kernel(const int* __restrict__ qw,
                                                      const float* __restrict__ sc,
                                                      const float* __restrict__ zp,
                                                      unsigned short* __restrict__ W) {
  size_t chunk = (size_t)blockIdx.x * 256 + threadIdx.x;  // 4 packed int32 = 8 weights
  int row = (int)(chunk >> 9);
  int c4  = (int)(chunk & 511);
  int g   = c4 >> 4;
  float s = sc[row * NGROUP + g];
  float z = zp[row * NGROUP + g];
  int4 q = *(const int4*)(qw + (size_t)row * 2048 + c4 * 4);
  int qq[4] = {q.x, q.y, q.z, q.w};
  short8 o;
#pragma unroll
  for (int t = 0; t < 4; ++t) {
    o[2 * t]     = (short)f2bf(((float)(qq[t] & 15)        - z) * s);
    o[2 * t + 1] = (short)f2bf(((float)((qq[t] >> 4) & 15) - z) * s);
  }
  *(short8*)(W + (size_t)row * K_DIM + (size_t)c4 * 8) = o;
}

// ---------- 128x256 GEMM, BK=32, TRIPLE-buffered LDS, 2 blocks/CU ----------
__device__ __forceinline__ void gload_lds16(const void* g, void* l) {
  __builtin_amdgcn_global_load_lds((__attribute__((address_space(1))) void*)g,
                                   (__attribute__((address_space(3))) void*)l,
                                   16, 0, 0);
}

#define VMC(N) asm volatile("s_waitcnt vmcnt(" #N ")" ::: "memory")

// One K-tile phase. Reads from (PA,PB); optionally stages tile T+2 into (SA,SB)
// (whose readers crossed the previous barrier -> dead >=1 barrier); 16 MFMA;
// counted VMC retires exactly next tile's 3 loads; barrier publishes.
#define TILE(PA, PB, SA, SB, KOFF, DO_STAGE, VM_STMT)                        \
  {                                                                          \
    bf16x8 av[4], bv[4];                                                     \
    _Pragma("unroll") for (int m_ = 0; m_ < 4; ++m_)                         \
      av[m_] = *(const bf16x8*)&(PA)[abase + m_ * 512];                      \
    _Pragma("unroll") for (int n_ = 0; n_ < 4; ++n_)                         \
      bv[n_] = *(const bf16x8*)&(PB)[bbase + n_ * 512];                      \
    if (DO_STAGE) {                                                          \
      gload_lds16(asrc0 + (KOFF), (SA) + wave * 512);                        \
      gload_lds16(bsrc0 + (KOFF), (SB) + wave * 512);                        \
      gload_lds16(bsrc1 + (KOFF), (SB) + 4096 + wave * 512);                 \
    }                                                                        \
    __builtin_amdgcn_s_setprio(1);                                           \
    _Pragma("unroll") for (int m_ = 0; m_ < 4; ++m_)                         \
      _Pragma("unroll") for (int n_ = 0; n_ < 4; ++n_)                       \
        acc[m_][n_] = __builtin_amdgcn_mfma_f32_16x16x32_bf16(               \
            av[m_], bv[n_], acc[m_][n_], 0, 0, 0);                           \
    __builtin_amdgcn_s_setprio(0);                                           \
    VM_STMT;                                                                 \
    __builtin_amdgcn_s_barrier();                                            \
  }

__global__ __launch_bounds__(512, 2) void gemm_occ_kernel(const unsigned short* __restrict__ A,
                                                          const unsigned short* __restrict__ B,
                                                          float* __restrict__ C) {
  extern __shared__ unsigned short lds[];
  // As: 3 bufs x [128][32] = 3 x 4096 elems (24KB); Bs: 3 x [256][32] (48KB). 72KB total.
  unsigned short* A0 = lds;
  unsigned short* A1 = lds + 4096;
  unsigned short* A2 = lds + 8192;
  unsigned short* B0 = lds + 12288;
  unsigned short* B1 = lds + 12288 + 8192;
  unsigned short* B2 = lds + 12288 + 16384;

  const int tid  = threadIdx.x;
  const int wave = tid >> 6;
  const int lane = tid & 63;
  const int wm = wave >> 2;   // 0..1 -> 64-row slab
  const int wn = wave & 3;    // 0..3 -> 64-col slab
  const int fr = lane & 15;
  const int cp = (lane >> 4) ^ ((fr >> 1) & 3);  // swizzled physical 16B-block (0-conflict)

  // XCD-chunked block swizzle (2752 = 8*344, bijective), bn-major:
  // 64 consecutive blocks on an XCD share one 2MB B-panel (L2-resident).
  const int wg  = blockIdx.x;
  const int sz_ = (wg & 7) * 344 + (wg >> 3);
  const int bn = sz_ >> 6;        // /64, 0..42
  const int bm = sz_ & 63;        // 0..63
  const size_t row0 = (size_t)bm * BM;
  const size_t col0 = (size_t)bn * BN;

  const unsigned short* Ab = A + row0 * K_DIM;
  const unsigned short* Bb = B + col0 * K_DIM;

  // per-lane staging sources (swizzle baked into global col, rule #21)
  const int cl = (tid & 3) ^ ((tid >> 3) & 3);
  const int r0 = tid >> 2;                      // 0..127
  const unsigned short* asrc0 = Ab + (size_t)r0 * K_DIM + cl * 8;
  const unsigned short* bsrc0 = Bb + (size_t)r0 * K_DIM + cl * 8;
  const unsigned short* bsrc1 = Bb + (size_t)(r0 + 128) * K_DIM + cl * 8;

  // fragment LDS element offsets (panel-local); frag i at base + i*512
  const int abase = (wm * 64 + fr) * 32 + cp * 8;
  const int bbase = (wn * 64 + fr) * 32 + cp * 8;

  f32x4 acc[4][4];
#pragma unroll
  for (int i = 0; i < 4; ++i)
#pragma unroll
    for (int j = 0; j < 4; ++j) acc[i][j] = (f32x4){0.f, 0.f, 0.f, 0.f};

  // ---- prologue: stage T0 -> buf0, T1 -> buf1 (3 loads each); retire T0's ----
  gload_lds16(asrc0, A0 + wave * 512);
  gload_lds16(bsrc0, B0 + wave * 512);
  gload_lds16(bsrc1, B0 + 4096 + wave * 512);
  gload_lds16(asrc0 + 32, A1 + wave * 512);
  gload_lds16(bsrc0 + 32, B1 + wave * 512);
  gload_lds16(bsrc1 + 32, B1 + 4096 + wave * 512);
  VMC(3);                       // T0's 3 landed; T1's in flight
  __builtin_amdgcn_s_barrier();

  // ---- main loop: unroll x3 for static buffer rotation; T = 0..NT-3 staged ----
  // NT=128: staged tiles T=0..125 (42 iters x 3), stage target T+2 <= 127.
  for (int T = 0; T < NT - 2; T += 3) {
    const int k2 = (T + 2) * 32;
    TILE(A0, B0, A2, B2, k2,      true, VMC(3));        // T   (buf0), stage T+2 -> buf2
    TILE(A1, B1, A0, B0, k2 + 32, true, VMC(3));        // T+1 (buf1), stage T+3 -> buf0
    TILE(A2, B2, A1, B1, k2 + 64, (T + 4) < NT, VMC(3)); // T+2 (buf2), stage T+4 -> buf1
  }
  // after loop: 126 tiles done (T=0..125). Remaining: T=126 (buf0), T=127 (buf1).
  // outstanding: T=127's 3 loads (issued at T=125).
  TILE(A0, B0, A0, B0, 0, false, VMC(0));               // T=126; drain T=127's loads
  {
    bf16x8 av[4], bv[4];
#pragma unroll
    for (int m_ = 0; m_ < 4; ++m_) av[m_] = *(const bf16x8*)&A1[abase + m_ * 512];
#pragma unroll
    for (int n_ = 0; n_ < 4; ++n_) bv[n_] = *(const bf16x8*)&B1[bbase + n_ * 512];
    __builtin_amdgcn_s_setprio(1);
#pragma unroll
    for (int m_ = 0; m_ < 4; ++m_)
#pragma unroll
      for (int n_ = 0; n_ < 4; ++n_)
        acc[m_][n_] = __builtin_amdgcn_mfma_f32_16x16x32_bf16(av[m_], bv[n_], acc[m_][n_], 0, 0, 0);
    __builtin_amdgcn_s_setprio(0);
  }

  // ---- epilogue: C/D layout col = lane&15, row = (lane>>4)*4 + v ----
  const int orow = (lane >> 4) * 4;
#pragma unroll
  for (int mi = 0; mi < 4; ++mi) {
#pragma unroll
    for (int n = 0; n < 4; ++n) {
      const size_t r = row0 + wm * 64 + mi * 16 + orow;
      const size_t c = col0 + wn * 64 + n * 16 + fr;
#pragma unroll
      for (int v = 0; v < 4; ++v)
        C[(r + v) * N_DIM + c] = acc[mi][n][v];
    }
  }
}

// ---------- fallback (only if d_ws too small): naive fused ----------
__global__ __launch_bounds__(256) void fallback_kernel(const float* __restrict__ x,
                                                       const int* __restrict__ qw,
                                                       const float* __restrict__ sc,
                                                       const float* __restrict__ zp,
                                                       float* __restrict__ out) {
  __shared__ float xs[K_DIM];
  const int m = blockIdx.y;
  const int n = blockIdx.x * 256 + threadIdx.x;
  for (int i = threadIdx.x; i < K_DIM; i += 256) xs[i] = x[(size_t)m * K_DIM + i];
  __syncthreads();
  float acc = 0.f;
  const int* wrow = qw + (size_t)n * (K_DIM / 2);
  for (int g = 0; g < NGROUP; ++g) {
    float s = sc[n * NGROUP + g];
    float z = zp[n * NGROUP + g];
    float partial = 0.f;
    for (int p = 0; p < 64; ++p) {
      int q = wrow[g * 64 + p];
      partial += xs[g * 128 + 2 * p]     * ((float)(q & 15) - z);
      partial += xs[g * 128 + 2 * p + 1] * ((float)((q >> 4) & 15) - z);
    }
    acc = fmaf(partial, s, acc);
  }
  out[(size_t)m * N_DIM + n] = acc;
}

extern "C" void kernel_launch(void* const* d_in, const int* in_sizes, int n_in,
                              void* d_out, int out_size, void* d_ws, size_t ws_size,
                              hipStream_t stream) {
  const float* x  = (const float*)d_in[0];
  const int*   qw = (const int*)d_in[1];
  const float* sc = (const float*)d_in[2];
  const float* zp = (const float*)d_in[3];
  float* out = (float*)d_out;

  const size_t xb_bytes = (size_t)M_DIM * K_DIM * 2;
  const size_t wb_bytes = (size_t)N_DIM * K_DIM * 2;

  if (ws_size >= xb_bytes + wb_bytes) {
    unsigned short* xb = (unsigned short*)d_ws;
    unsigned short* wb = (unsigned short*)((char*)d_ws + xb_bytes);
    cvt_x_kernel<<<dim3((unsigned)((size_t)M_DIM * K_DIM / (256 * 8))), 256, 0, stream>>>(x, xb);
    dequant_kernel<<<dim3((unsigned)((size_t)N_DIM * (K_DIM / 2) / 4 / 256)), 256, 0, stream>>>(qw, sc, zp, wb);
    dim3 grid((M_DIM / BM) * (N_DIM / BN));  // 64*43 = 2752 = 8*344
    gemm_occ_kernel<<<grid, dim3(512), 73728, stream>>>(xb, wb, out);
  } else {
    dim3 grid(N_DIM / 256, M_DIM);
    fallback_kernel<<<grid, 256, 0, stream>>>(x, qw, sc, zp, out);
  }
}